// Round 14
// baseline (219.347 us; speedup 1.0000x reference)
//
#include <hip/hip_runtime.h>

typedef __attribute__((ext_vector_type(8))) __bf16 bf16x8;
typedef __attribute__((ext_vector_type(4))) float f32x4;

#define N_SAMP 256
#define DIM    2048
#define NCENT  32000
#define INV_T  14.285714285714285714f   // 1 / 0.07
#define NWG    500                       // one 256x64 tile per block (4 waves)
#define NTILE  64                        // K / 32

// A pre-packed in MFMA-fragment order (R13-verified):
//   byte addr = tile*16384 + grp*1024 + lane*16
//   (tile = k>>5, grp = row>>4, lane = (row&15)|(((k>>3)&3)<<4))

// ---- kernel 1: normalize feats -> bf16 fragment-packed; zero d_acc ----
__global__ __launch_bounds__(256) void norm_kernel(const float* __restrict__ feats,
                                                   char* __restrict__ fnorm_pk,
                                                   float* __restrict__ d_acc) {
    int row = blockIdx.x;
    int tid = threadIdx.x;
    if (row < 16) d_acc[row * 256 + tid] = 0.f;   // zero 8 slots x 512 floats
    const float* src = feats + (size_t)row * DIM;
    float4 v0 = reinterpret_cast<const float4*>(src)[2 * tid];
    float4 v1 = reinterpret_cast<const float4*>(src)[2 * tid + 1];
    float ss = v0.x * v0.x + v0.y * v0.y + v0.z * v0.z + v0.w * v0.w
             + v1.x * v1.x + v1.y * v1.y + v1.z * v1.z + v1.w * v1.w;
    #pragma unroll
    for (int off = 1; off < 64; off <<= 1) ss += __shfl_xor(ss, off, 64);
    __shared__ float wsum[4];
    if ((tid & 63) == 0) wsum[tid >> 6] = ss;
    __syncthreads();
    float inv = 1.0f / sqrtf(wsum[0] + wsum[1] + wsum[2] + wsum[3]);
    bf16x8 o;
    o[0] = (__bf16)(v0.x * inv); o[1] = (__bf16)(v0.y * inv);
    o[2] = (__bf16)(v0.z * inv); o[3] = (__bf16)(v0.w * inv);
    o[4] = (__bf16)(v1.x * inv); o[5] = (__bf16)(v1.y * inv);
    o[6] = (__bf16)(v1.z * inv); o[7] = (__bf16)(v1.w * inv);
    int tile = tid >> 2, ksub = tid & 3;
    int grp  = row >> 4;
    int lane = (row & 15) | (ksub << 4);
    *reinterpret_cast<bf16x8*>(fnorm_pk
        + ((size_t)tile * 16 + grp) * 1024 + lane * 16) = o;
}

// ---- kernel 2: barrier-free streaming GEMM. 500 blocks x 256 thr (4 waves). ----
// Block owns 64 centers; wave w computes rows [w*64, w*64+64) x all 64 centers.
// No LDS, no syncs: A frags direct from packed global (L2), B frags direct from
// centers (f32 -> cvt in reg); 4 waves read identical B lines -> L1 absorbs.
__global__ __launch_bounds__(256, 3) void sims_kernel(
    const char* __restrict__ fnorm_pk, const float* __restrict__ centers,
    const int* __restrict__ labels, const int* __restrict__ camids,
    float* __restrict__ d_acc, float* __restrict__ d_own)
{
    const int tid  = threadIdx.x;
    const int wave = tid >> 6;
    const int lane = tid & 63;
    const int l15  = lane & 15;
    const int lhi  = lane >> 4;

    const int nb    = blockIdx.x;        // 0..499
    const int cbase = nb * 64;

    f32x4 acc[4][4] = {};

    // A: this wave's 4 row-groups, lane-packed
    const char* apk = fnorm_pk + (size_t)wave * 4096 + lane * 16;
    // B: 4 n-frag row bases; lane reads 32 B at k-offset
    const float* bp0 = centers + (size_t)(cbase + 0 * 16 + l15) * DIM + lhi * 8;
    const float* bp1 = centers + (size_t)(cbase + 1 * 16 + l15) * DIM + lhi * 8;
    const float* bp2 = centers + (size_t)(cbase + 2 * 16 + l15) * DIM + lhi * 8;
    const float* bp3 = centers + (size_t)(cbase + 3 * 16 + l15) * DIM + lhi * 8;

    #pragma unroll 2
    for (int t = 0; t < NTILE; ++t) {
        // A first (L2 ~200cy), B second (HBM) -> A waits don't chain on B latency
        bf16x8 af0 = *reinterpret_cast<const bf16x8*>(apk + (size_t)t * 16384);
        bf16x8 af1 = *reinterpret_cast<const bf16x8*>(apk + (size_t)t * 16384 + 1024);
        bf16x8 af2 = *reinterpret_cast<const bf16x8*>(apk + (size_t)t * 16384 + 2048);
        bf16x8 af3 = *reinterpret_cast<const bf16x8*>(apk + (size_t)t * 16384 + 3072);

        float4 x0 = *reinterpret_cast<const float4*>(bp0 + t * 32);
        float4 y0 = *reinterpret_cast<const float4*>(bp0 + t * 32 + 4);
        float4 x1 = *reinterpret_cast<const float4*>(bp1 + t * 32);
        float4 y1 = *reinterpret_cast<const float4*>(bp1 + t * 32 + 4);
        float4 x2 = *reinterpret_cast<const float4*>(bp2 + t * 32);
        float4 y2 = *reinterpret_cast<const float4*>(bp2 + t * 32 + 4);
        float4 x3 = *reinterpret_cast<const float4*>(bp3 + t * 32);
        float4 y3 = *reinterpret_cast<const float4*>(bp3 + t * 32 + 4);

        bf16x8 bf0, bf1, bf2, bf3;
        bf0[0] = (__bf16)x0.x; bf0[1] = (__bf16)x0.y; bf0[2] = (__bf16)x0.z; bf0[3] = (__bf16)x0.w;
        bf0[4] = (__bf16)y0.x; bf0[5] = (__bf16)y0.y; bf0[6] = (__bf16)y0.z; bf0[7] = (__bf16)y0.w;
        bf1[0] = (__bf16)x1.x; bf1[1] = (__bf16)x1.y; bf1[2] = (__bf16)x1.z; bf1[3] = (__bf16)x1.w;
        bf1[4] = (__bf16)y1.x; bf1[5] = (__bf16)y1.y; bf1[6] = (__bf16)y1.z; bf1[7] = (__bf16)y1.w;
        bf2[0] = (__bf16)x2.x; bf2[1] = (__bf16)x2.y; bf2[2] = (__bf16)x2.z; bf2[3] = (__bf16)x2.w;
        bf2[4] = (__bf16)y2.x; bf2[5] = (__bf16)y2.y; bf2[6] = (__bf16)y2.z; bf2[7] = (__bf16)y2.w;
        bf3[0] = (__bf16)x3.x; bf3[1] = (__bf16)x3.y; bf3[2] = (__bf16)x3.z; bf3[3] = (__bf16)x3.w;
        bf3[4] = (__bf16)y3.x; bf3[5] = (__bf16)y3.y; bf3[6] = (__bf16)y3.z; bf3[7] = (__bf16)y3.w;

        #pragma unroll
        for (int mi = 0; mi < 4; ++mi) {
            bf16x8 af = mi == 0 ? af0 : mi == 1 ? af1 : mi == 2 ? af2 : af3;
            acc[mi][0] = __builtin_amdgcn_mfma_f32_16x16x32_bf16(af, bf0, acc[mi][0], 0, 0, 0);
            acc[mi][1] = __builtin_amdgcn_mfma_f32_16x16x32_bf16(af, bf1, acc[mi][1], 0, 0, 0);
            acc[mi][2] = __builtin_amdgcn_mfma_f32_16x16x32_bf16(af, bf2, acc[mi][2], 0, 0, 0);
            acc[mi][3] = __builtin_amdgcn_mfma_f32_16x16x32_bf16(af, bf3, acc[mi][3], 0, 0, 0);
        }
    }

    // ---- epilogue: exp + masks + per-sample partial denominators ----
    float* slot_acc = d_acc + (nb & 7) * 512;
    #pragma unroll
    for (int mi = 0; mi < 4; ++mi) {
        #pragma unroll
        for (int r = 0; r < 4; ++r) {
            int i   = wave * 64 + mi * 16 + lhi * 4 + r;
            int lab = labels[i], cam = camids[i];
            int oidx = lab * 8 + cam;
            float pi = 0.f, pj = 0.f;
            #pragma unroll
            for (int ni = 0; ni < 4; ++ni) {
                int c = cbase + ni * 16 + l15;
                float s = acc[mi][ni][r] * INV_T;
                float e = __expf(s);
                if ((l15 & 7) == cam) pi += e;          // c % 8 == cam
                bool ol = ((c >> 3) == lab);
                bool hard = (!ol) && (c < ((c < lab * 8) ? 50 : 58));
                if (ol || hard) pj += e;
                if (c == oidx) d_own[i] = s;
            }
            #pragma unroll
            for (int off = 1; off < 16; off <<= 1) {
                pi += __shfl_xor(pi, off, 64);
                pj += __shfl_xor(pj, off, 64);
            }
            if (l15 == 0) {
                atomicAdd(&slot_acc[i], pi);
                atomicAdd(&slot_acc[N_SAMP + i], pj);
            }
        }
    }
}

// ---------------- kernel 3: finalize (segment means + output) ----------------
__global__ __launch_bounds__(256) void finalize_kernel(
    const float* __restrict__ d_acc, const float* __restrict__ d_own,
    const int* __restrict__ labels, const int* __restrict__ camids,
    float* __restrict__ out, int out_size)
{
    __shared__ int s_lab[N_SAMP], s_cam[N_SAMP];
    __shared__ float wsum[8];
    int tid = threadIdx.x;
    s_lab[tid] = labels[tid];
    s_cam[tid] = camids[tid];
    __syncthreads();
    int myl = s_lab[tid], myc = s_cam[tid];
    int nl = 0, nc = 0;
    for (int j = 0; j < N_SAMP; ++j) {
        nl += (s_lab[j] == myl);
        nc += (s_cam[j] == myc);
    }
    float di = 0.f, dj = 0.f;
    #pragma unroll
    for (int s = 0; s < 8; ++s) {
        di += d_acc[s * 512 + tid];
        dj += d_acc[s * 512 + 256 + tid];
    }
    float own = d_own[tid];
    float li = own - logf(di);
    float lj = own - logf(dj);
    float a = li / (float)nc;   // sum_i loss_i / n_cam == sum over cams of per-cam mean
    float b = lj / (float)nl;
    #pragma unroll
    for (int off = 1; off < 64; off <<= 1) {
        a += __shfl_xor(a, off, 64);
        b += __shfl_xor(b, off, 64);
    }
    if ((tid & 63) == 0) { wsum[tid >> 6] = a; wsum[4 + (tid >> 6)] = b; }
    __syncthreads();
    if (tid == 0) {
        float sa = wsum[0] + wsum[1] + wsum[2] + wsum[3];
        float sb = wsum[4] + wsum[5] + wsum[6] + wsum[7];
        out[0] = -sa;
        if (out_size > 1) out[1] = -0.5f * sb;   // LAMDA = 0.5
    }
}

extern "C" void kernel_launch(void* const* d_in, const int* in_sizes, int n_in,
                              void* d_out, int out_size, void* d_ws, size_t ws_size,
                              hipStream_t stream) {
    const float* feats   = (const float*)d_in[0];
    const float* centers = (const float*)d_in[1];
    const int*   labels  = (const int*)d_in[2];
    const int*   camids  = (const int*)d_in[3];
    float* out = (float*)d_out;

    char*  fnorm_pk = (char*)d_ws;                                   // 1 MB packed
    float* d_acc    = (float*)((char*)d_ws + (size_t)1048576);       // 8 slots x 512
    float* d_own    = d_acc + 8 * 2 * N_SAMP;                        // 256

    norm_kernel<<<N_SAMP, 256, 0, stream>>>(feats, fnorm_pk, d_acc);
    sims_kernel<<<NWG, 256, 0, stream>>>(fnorm_pk, centers, labels, camids, d_acc, d_own);
    finalize_kernel<<<1, 256, 0, stream>>>(d_acc, d_own, labels, camids, out, out_size);
}

// Round 15
// 91.410 us; speedup vs baseline: 2.3996x; 2.3996x over previous
//
#include <hip/hip_runtime.h>

typedef __attribute__((ext_vector_type(8))) __bf16 bf16x8;
typedef __attribute__((ext_vector_type(4))) float f32x4;

#define N_SAMP 256
#define DIM    2048
#define NCENT  32000
#define INV_T  14.285714285714285714f   // 1 / 0.07
#define NWG    250                       // one 256x128 tile per block
#define NTILE  32                        // K / BK = 2048 / 64

// A pre-packed in MFMA-fragment order (R13-verified):
//   byte = tile*16384 + grp*1024 + lane*16   (tile=k>>5, grp=row>>4, lane=(row&15)|(((k>>3)&3)<<4))
// B LDS tile (f32, 32 KB): [128 rows][16 units of 16B], stored unit' = unit ^ (row&15).
//   DMA writes linearly (dest = wave base + lane*16); SOURCE is pre-swizzled.
//   Read at logical unit u: physical u ^ l15 -> 16 distinct units per lane-group = conflict-free.

// ---- kernel 1: normalize feats -> bf16 fragment-packed; zero d_acc ----
__global__ __launch_bounds__(256) void norm_kernel(const float* __restrict__ feats,
                                                   char* __restrict__ fnorm_pk,
                                                   float* __restrict__ d_acc) {
    int row = blockIdx.x;
    int tid = threadIdx.x;
    if (row < 16) d_acc[row * 256 + tid] = 0.f;   // zero 8 slots x 512 floats
    const float* src = feats + (size_t)row * DIM;
    float4 v0 = reinterpret_cast<const float4*>(src)[2 * tid];
    float4 v1 = reinterpret_cast<const float4*>(src)[2 * tid + 1];
    float ss = v0.x * v0.x + v0.y * v0.y + v0.z * v0.z + v0.w * v0.w
             + v1.x * v1.x + v1.y * v1.y + v1.z * v1.z + v1.w * v1.w;
    #pragma unroll
    for (int off = 1; off < 64; off <<= 1) ss += __shfl_xor(ss, off, 64);
    __shared__ float wsum[4];
    if ((tid & 63) == 0) wsum[tid >> 6] = ss;
    __syncthreads();
    float inv = 1.0f / sqrtf(wsum[0] + wsum[1] + wsum[2] + wsum[3]);
    bf16x8 o;
    o[0] = (__bf16)(v0.x * inv); o[1] = (__bf16)(v0.y * inv);
    o[2] = (__bf16)(v0.z * inv); o[3] = (__bf16)(v0.w * inv);
    o[4] = (__bf16)(v1.x * inv); o[5] = (__bf16)(v1.y * inv);
    o[6] = (__bf16)(v1.z * inv); o[7] = (__bf16)(v1.w * inv);
    int tile = tid >> 2, ksub = tid & 3;
    int grp  = row >> 4;
    int lane = (row & 15) | (ksub << 4);
    *reinterpret_cast<bf16x8*>(fnorm_pk
        + ((size_t)tile * 16 + grp) * 1024 + lane * 16) = o;
}

// ---- kernel 2: 256x128 tile, BK=64; B via global_load_lds (f32), A packed-direct ----
// 250 blocks x 512 threads (8 waves = 4m x 2n; wave tile 64x64, acc 4x4).
// Triple-buffered B, DMA issued 2 steps ahead; A-loads issued BEFORE the DMA so
// the compiler's in-order A-waits never drain the prefetch queue.
__global__ __launch_bounds__(512, 2) void sims_kernel(
    const char* __restrict__ fnorm_pk, const float* __restrict__ centers,
    const int* __restrict__ labels, const int* __restrict__ camids,
    float* __restrict__ d_acc, float* __restrict__ d_own)
{
    __shared__ __align__(16) char sB[3][32768];

    const int tid  = threadIdx.x;
    const int wave = tid >> 6;
    const int lane = tid & 63;
    const int l15  = lane & 15;
    const int lhi  = lane >> 4;

    const int nb    = blockIdx.x;        // 0..249
    const int cbase = nb * 128;

    const int wr = (wave >> 1) * 64;     // wave rows in 256
    const int wc = (wave & 1) * 64;      // wave cols in 128

    f32x4 acc[4][4] = {};

    // DMA source pointers: 4 chunks/thread; chunk i covers rows wave*16+i*4 .. +3
    const char* csrc[4];
    #pragma unroll
    for (int i = 0; i < 4; ++i) {
        int row = wave * 16 + i * 4 + (lane >> 4);
        int u   = (lane & 15) ^ (row & 15);
        csrc[i] = (const char*)centers + (size_t)(cbase + row) * 8192 + u * 16;
    }
    const char* apk = fnorm_pk + (size_t)(wave >> 1) * 4096 + lane * 16;

    auto dma = [&](int t, int buf) {
        #pragma unroll
        for (int i = 0; i < 4; ++i)
            __builtin_amdgcn_global_load_lds(
                (const unsigned int*)(csrc[i] + (size_t)t * 256),
                (unsigned int*)&sB[buf][wave * 4096 + i * 1024], 16, 0, 0);
    };

    dma(0, 0);
    dma(1, 1);
    asm volatile("s_waitcnt vmcnt(4)" ::: "memory");   // buf0 complete; buf1 in flight
    __builtin_amdgcn_s_barrier();

    int buf = 0;
    for (int t = 0; t < NTILE; ++t) {
        // A fragments first (newer than outstanding DMAs -> waits don't drain prefetch)
        bf16x8 af0[4], af1[4];
        {
            const char* p0 = apk + (size_t)(2 * t) * 16384;
            #pragma unroll
            for (int mi = 0; mi < 4; ++mi) {
                af0[mi] = *reinterpret_cast<const bf16x8*>(p0 + mi * 1024);
                af1[mi] = *reinterpret_cast<const bf16x8*>(p0 + 16384 + mi * 1024);
            }
        }
        if (t + 2 < NTILE) dma(t + 2, buf == 0 ? 2 : buf - 1);   // (t+2)%3

        #pragma unroll
        for (int s = 0; s < 2; ++s) {
            #pragma unroll
            for (int ni = 0; ni < 4; ++ni) {
                int row  = wc + ni * 16 + l15;
                int base = row * 256;
                int u0   = (s * 8 + lhi * 2) ^ l15;        // row&15 == l15
                int u1   = u0 ^ 1;
                float4 x = *reinterpret_cast<const float4*>(&sB[buf][base + u0 * 16]);
                float4 y = *reinterpret_cast<const float4*>(&sB[buf][base + u1 * 16]);
                bf16x8 b;
                b[0] = (__bf16)x.x; b[1] = (__bf16)x.y; b[2] = (__bf16)x.z; b[3] = (__bf16)x.w;
                b[4] = (__bf16)y.x; b[5] = (__bf16)y.y; b[6] = (__bf16)y.z; b[7] = (__bf16)y.w;
                const bf16x8* af = s ? af1 : af0;
                #pragma unroll
                for (int mi = 0; mi < 4; ++mi)
                    acc[mi][ni] = __builtin_amdgcn_mfma_f32_16x16x32_bf16(
                        af[mi], b, acc[mi][ni], 0, 0, 0);
            }
        }

        asm volatile("s_waitcnt vmcnt(4)" ::: "memory");   // next buf's DMA complete
        asm volatile("s_waitcnt lgkmcnt(0)" ::: "memory"); // our ds_reads drained
        __builtin_amdgcn_s_barrier();
        buf = (buf == 2) ? 0 : buf + 1;
    }

    // ---- epilogue: exp + masks + per-sample partial denominators ----
    float* slot_acc = d_acc + (nb & 7) * 512;
    #pragma unroll
    for (int mi = 0; mi < 4; ++mi) {
        #pragma unroll
        for (int r = 0; r < 4; ++r) {
            int i   = wr + mi * 16 + lhi * 4 + r;
            int lab = labels[i], cam = camids[i];
            int oidx = lab * 8 + cam;
            float pi = 0.f, pj = 0.f;
            #pragma unroll
            for (int ni = 0; ni < 4; ++ni) {
                int c = cbase + wc + ni * 16 + l15;
                float s = acc[mi][ni][r] * INV_T;
                float e = __expf(s);
                if ((l15 & 7) == cam) pi += e;          // c % 8 == cam
                bool ol = ((c >> 3) == lab);
                bool hard = (!ol) && (c < ((c < lab * 8) ? 50 : 58));
                if (ol || hard) pj += e;
                if (c == oidx) d_own[i] = s;
            }
            #pragma unroll
            for (int off = 1; off < 16; off <<= 1) {
                pi += __shfl_xor(pi, off, 64);
                pj += __shfl_xor(pj, off, 64);
            }
            if (l15 == 0) {
                atomicAdd(&slot_acc[i], pi);
                atomicAdd(&slot_acc[N_SAMP + i], pj);
            }
        }
    }
}

// ---------------- kernel 3: finalize (segment means + output) ----------------
__global__ __launch_bounds__(256) void finalize_kernel(
    const float* __restrict__ d_acc, const float* __restrict__ d_own,
    const int* __restrict__ labels, const int* __restrict__ camids,
    float* __restrict__ out, int out_size)
{
    __shared__ int s_lab[N_SAMP], s_cam[N_SAMP];
    __shared__ float wsum[8];
    int tid = threadIdx.x;
    s_lab[tid] = labels[tid];
    s_cam[tid] = camids[tid];
    __syncthreads();
    int myl = s_lab[tid], myc = s_cam[tid];
    int nl = 0, nc = 0;
    for (int j = 0; j < N_SAMP; ++j) {
        nl += (s_lab[j] == myl);
        nc += (s_cam[j] == myc);
    }
    float di = 0.f, dj = 0.f;
    #pragma unroll
    for (int s = 0; s < 8; ++s) {
        di += d_acc[s * 512 + tid];
        dj += d_acc[s * 512 + 256 + tid];
    }
    float own = d_own[tid];
    float li = own - logf(di);
    float lj = own - logf(dj);
    float a = li / (float)nc;   // sum_i loss_i / n_cam == sum over cams of per-cam mean
    float b = lj / (float)nl;
    #pragma unroll
    for (int off = 1; off < 64; off <<= 1) {
        a += __shfl_xor(a, off, 64);
        b += __shfl_xor(b, off, 64);
    }
    if ((tid & 63) == 0) { wsum[tid >> 6] = a; wsum[4 + (tid >> 6)] = b; }
    __syncthreads();
    if (tid == 0) {
        float sa = wsum[0] + wsum[1] + wsum[2] + wsum[3];
        float sb = wsum[4] + wsum[5] + wsum[6] + wsum[7];
        out[0] = -sa;
        if (out_size > 1) out[1] = -0.5f * sb;   // LAMDA = 0.5
    }
}

extern "C" void kernel_launch(void* const* d_in, const int* in_sizes, int n_in,
                              void* d_out, int out_size, void* d_ws, size_t ws_size,
                              hipStream_t stream) {
    const float* feats   = (const float*)d_in[0];
    const float* centers = (const float*)d_in[1];
    const int*   labels  = (const int*)d_in[2];
    const int*   camids  = (const int*)d_in[3];
    float* out = (float*)d_out;

    char*  fnorm_pk = (char*)d_ws;                                   // 1 MB packed
    float* d_acc    = (float*)((char*)d_ws + (size_t)1048576);       // 8 slots x 512
    float* d_own    = d_acc + 8 * 2 * N_SAMP;                        // 256

    norm_kernel<<<N_SAMP, 256, 0, stream>>>(feats, fnorm_pk, d_acc);
    sims_kernel<<<NWG, 512, 0, stream>>>(fnorm_pk, centers, labels, camids, d_acc, d_own);
    finalize_kernel<<<1, 256, 0, stream>>>(d_acc, d_own, labels, camids, out, out_size);
}